// Round 1
// baseline (42.396 us; speedup 1.0000x reference)
//
#include <hip/hip_runtime.h>
#include <hip/hip_bf16.h>

// InvertedReorg: inverse pixel-shuffle, s=2.
// in:  (32, 256, 64, 64) f32
// out: (32, 64, 128, 128) f32
// out[b][c][s1*64+hh][s2*64+ww] = in[b][s1*128 + s2*64 + c][hh][ww]
//
// One thread per output float4. Output write is perfectly linear; input read
// is contiguous within each 64-float segment (s2 fixed inside a float4 since
// W=64 % 4 == 0). All decompositions are shifts/masks (power-of-2 dims).

__global__ __launch_bounds__(256) void inverted_reorg_kernel(
    const float4* __restrict__ in, float4* __restrict__ out) {
    unsigned t = blockIdx.x * blockDim.x + threadIdx.x;  // float4 index, 0..2^23-1

    // out float4 layout: b(32) . cc(64) . oh(128) . ow4(32)
    unsigned ow4 = t & 31u;          // float4 within output row (128/4)
    unsigned oh  = (t >> 5) & 127u;
    unsigned cc  = (t >> 12) & 63u;
    unsigned b   = t >> 18;

    unsigned ow = ow4 << 2;
    unsigned s1 = oh >> 6, hh = oh & 63u;
    unsigned s2 = ow >> 6, ww = ow & 63u;
    unsigned ch = (s1 << 7) + (s2 << 6) + cc;   // s1*128 + s2*64 + cc

    // input flat float index: ((b*256 + ch)*64 + hh)*64 + ww  -> float4 units
    unsigned in4 = ((((b << 8) + ch) << 6) + hh) * 16u + (ww >> 2);

    out[t] = in[in4];
}

extern "C" void kernel_launch(void* const* d_in, const int* in_sizes, int n_in,
                              void* d_out, int out_size, void* d_ws, size_t ws_size,
                              hipStream_t stream) {
    const float4* in  = (const float4*)d_in[0];
    float4*       out = (float4*)d_out;

    // out_size = 32*64*128*128 = 33,554,432 floats = 8,388,608 float4s
    const int n4 = out_size / 4;               // 8,388,608
    const int block = 256;
    const int grid = n4 / block;               // 32,768 — exact, no tail
    inverted_reorg_kernel<<<grid, block, 0, stream>>>(in, out);
}